// Round 7
// baseline (5424.829 us; speedup 1.0000x reference)
//
#include <hip/hip_runtime.h>

#define Bdim 64
#define Hdim 1024
#define Vdim 32000
#define Tdim 40

typedef __bf16 bf16x8 __attribute__((ext_vector_type(8)));
typedef float  f32x4  __attribute__((ext_vector_type(4)));
typedef unsigned short u16x8 __attribute__((ext_vector_type(8)));
static_assert(sizeof(bf16x8) == 16, "bf16x8 must be 16B");

// Order-preserving float->uint32 map; pack with (0xFFFFFFFF - v) so that
// u64 max == (max value, lowest index on exact ties) — matches np.argmax.
__device__ __forceinline__ unsigned long long pack_key(float f, int v) {
    unsigned u = __float_as_uint(f);
    u = (u & 0x80000000u) ? ~u : (u | 0x80000000u);
    return ((unsigned long long)u << 32) | (unsigned long long)(0xFFFFFFFFu - (unsigned)v);
}

__device__ __forceinline__ int decode_key(unsigned long long key) {
    return (int)(0xFFFFFFFFu - (unsigned)(key & 0xFFFFFFFFull));
}

__device__ __forceinline__ void gll16(const void* g, void* l) {
    __builtin_amdgcn_global_load_lds(
        (const __attribute__((address_space(1))) void*)g,
        (__attribute__((address_space(3))) void*)l, 16, 0, 0);
}

struct BSplit { unsigned short h, m, l; };

// f32 -> bf16 hi/mid/lo (24-bit effective mantissa; residual ~2^-25 relative)
__device__ __forceinline__ BSplit bsplit3v(float x) {
    __bf16 h = (__bf16)x;  float r  = x - (float)h;
    __bf16 m = (__bf16)r;  float r2 = r - (float)m;
    __bf16 l = (__bf16)r2;
    BSplit s;
    s.h = __builtin_bit_cast(unsigned short, h);
    s.m = __builtin_bit_cast(unsigned short, m);
    s.l = __builtin_bit_cast(unsigned short, l);
    return s;
}

__device__ __forceinline__ void bsplit3(float x, unsigned short& a, unsigned short& b,
                                        unsigned short& c) {
    BSplit s = bsplit3v(x);
    a = s.h; b = s.m; c = s.l;
}

// ======================= k_logits: 128v x 64b, A in registers ===============
// Cycle model (r6 post-mortem): old version was bound by per-CU LDS reads
// (8 waves x 14 ds_read_b128/chunk = 1344 cyc) + 28KB stage drain per chunk
// => ~43us. A (h planes, 384KB, L1/L2-resident) was read redundantly by all
// 8 waves from LDS. Fix: A fragments are loaded per-wave straight from global
// into registers (4bt x 3planes x dwordx4, 16B-aligned, L1-hit after warmup),
// double-buffered via even/odd unroll (static indexing, rule #20). LDS keeps
// only W (2 x 16KB double buffer): 2 ds_read_b128/wave/chunk, 16KB stage.
// W staging swizzle + fragment math + epilogue/argmax identical to the
// round-5 harness-verified code.
template<bool AM>
__global__ __launch_bounds__(512, 1) void k_logits(
    const float* __restrict__ w_out,
    const unsigned short* __restrict__ ah, const unsigned short* __restrict__ am,
    const unsigned short* __restrict__ al,
    const float* __restrict__ b_out, float* __restrict__ out,
    unsigned long long* __restrict__ slots)
{
    constexpr int NW = 8, NCH = 32;
    constexpr int WBYTES = NW * 2048;          // 16384: W tile 128 rows x 128 B
    __shared__ __align__(16) unsigned char smem[2][WBYTES];
    __shared__ unsigned long long red[NW][4][16];

    const int tid  = threadIdx.x;
    const int lane = tid & 63;
    const int wid  = tid >> 6;
    const int vb   = blockIdx.x * 128;

    const unsigned char* Wb = (const unsigned char*)(w_out + (size_t)vb * Hdim);

    f32x4 acc[4] = {};

    const int col = lane & 15;
    const int kg  = lane >> 4;

    // W stage: 1024 granules (128 rows x 8x16B), 2/thread, swizzle g^(row&7)
    auto stageW = [&](int bufidx, int ch) {
        unsigned char* bb = smem[bufidx];
        const size_t kb4 = (size_t)ch * 128;   // 32 f32 = 128 B
#pragma unroll
        for (int s = 0; s < 2; s++) {
            int gg = tid + 512 * s;
            int rw = gg >> 3, cc = gg & 7;
            int sg = cc ^ (rw & 7);
            gll16(Wb + (size_t)rw * 4096 + kb4 + (size_t)sg * 16,
                  bb + ((wid * 64 + 512 * s) << 4));
        }
    };

    // A fragments for chunk ch -> regs: a[bt*3+p] = plane_p[bt*16+col][ch*32+kg*8 ..+8]
    // byte addr = row*2048 + ch*64 + kg*16 — 16B-aligned => global_load_dwordx4.
    auto loadA = [&](bf16x8* a, int ch) {
#pragma unroll
        for (int bt = 0; bt < 4; bt++) {
            const size_t ro = (size_t)(bt * 16 + col) * 1024 + (size_t)ch * 32 + kg * 8;
            a[bt * 3 + 0] = *(const bf16x8*)(ah + ro);
            a[bt * 3 + 1] = *(const bf16x8*)(am + ro);
            a[bt * 3 + 2] = *(const bf16x8*)(al + ro);
        }
    };

    const int wrow = wid * 16 + col;           // this wave's n-row within tile
    const int wg0  = (2 * kg) ^ (wrow & 7);
    const int wg1  = (2 * kg + 1) ^ (wrow & 7);

    auto compute = [&](const unsigned char* base, const bf16x8* a) {
        // W fragment: 8 contiguous f32 at row wrow (two swizzled 16B reads), split
        const unsigned char* Wr = base + wrow * 128;
        f32x4 w0 = *(const f32x4*)(Wr + (wg0 << 4));
        f32x4 w1 = *(const f32x4*)(Wr + (wg1 << 4));
        bf16x8 whi, wmid, wlo;
#pragma unroll
        for (int j = 0; j < 4; j++) {
            float x0 = w0[j], x1 = w1[j];
            __bf16 a0 = (__bf16)x0; float r0 = x0 - (float)a0;
            __bf16 b0 = (__bf16)r0; float q0 = r0 - (float)b0;
            whi[j] = a0; wmid[j] = b0; wlo[j] = (__bf16)q0;
            __bf16 a1 = (__bf16)x1; float r1 = x1 - (float)a1;
            __bf16 b1 = (__bf16)r1; float q1 = r1 - (float)b1;
            whi[4 + j] = a1; wmid[4 + j] = b1; wlo[4 + j] = (__bf16)q1;
        }
#pragma unroll
        for (int bt = 0; bt < 4; bt++) {
            bf16x8 ahi = a[bt * 3 + 0];
            bf16x8 ami = a[bt * 3 + 1];
            bf16x8 alo = a[bt * 3 + 2];
            acc[bt] = __builtin_amdgcn_mfma_f32_16x16x32_bf16(whi,  ahi, acc[bt], 0, 0, 0);
            acc[bt] = __builtin_amdgcn_mfma_f32_16x16x32_bf16(whi,  ami, acc[bt], 0, 0, 0);
            acc[bt] = __builtin_amdgcn_mfma_f32_16x16x32_bf16(wmid, ahi, acc[bt], 0, 0, 0);
            acc[bt] = __builtin_amdgcn_mfma_f32_16x16x32_bf16(whi,  alo, acc[bt], 0, 0, 0);
            acc[bt] = __builtin_amdgcn_mfma_f32_16x16x32_bf16(wlo,  ahi, acc[bt], 0, 0, 0);
            acc[bt] = __builtin_amdgcn_mfma_f32_16x16x32_bf16(wmid, ami, acc[bt], 0, 0, 0);
        }
    };

    // prologue
    bf16x8 aA[12], aB[12];
    loadA(aA, 0);
    stageW(0, 0);
    __syncthreads();     // drains vmcnt(0): W(0) in LDS, aA complete

    // even/odd unrolled double buffer: stage+loadA for ch+1 issued before
    // compute(ch) so they overlap the MFMA/VALU work; __syncthreads drains.
    for (int ch = 0; ch < NCH; ch += 2) {
        stageW(1, ch + 1);
        loadA(aB, ch + 1);
        compute(smem[0], aA);
        __syncthreads();
        if (ch + 2 < NCH) { stageW(0, ch + 2); loadA(aA, ch + 2); }
        compute(smem[1], aB);
        __syncthreads();
    }

    // epilogue: bias add, f32x4 store, block argmax
    const int ncol = vb + wid * 16 + kg * 4;
    f32x4 bv = *(const f32x4*)(b_out + ncol);

    unsigned long long bk[4];
#pragma unroll
    for (int bt = 0; bt < 4; bt++) {
        const int b = bt * 16 + col;
        float* op = out + (size_t)b * ((size_t)Tdim * Vdim) + ncol;
        f32x4 vv;
        unsigned long long best = 0ull;
#pragma unroll
        for (int r = 0; r < 4; r++) {
            float val = acc[bt][r] + bv[r];
            vv[r] = val;
            if (AM) {
                unsigned long long key = pack_key(val, ncol + r);
                if (key > best) best = key;
            }
        }
        *(f32x4*)op = vv;
        bk[bt] = best;
    }

    if constexpr (AM) {
#pragma unroll
        for (int bt = 0; bt < 4; bt++) {
            unsigned long long k = bk[bt];
            unsigned long long o = __shfl_xor(k, 16, 64); if (o > k) k = o;
            o = __shfl_xor(k, 32, 64);                    if (o > k) k = o;
            if (lane < 16) red[wid][bt][lane] = k;
        }
        __syncthreads();
        if (tid < 64) {
            const int bt = tid >> 4, c = tid & 15;
            unsigned long long k = red[0][bt][c];
#pragma unroll
            for (int w = 1; w < NW; w++)
                if (red[w][bt][c] > k) k = red[w][bt][c];
            atomicMax(&slots[bt * 16 + c], k);
        }
    }
}

// ==================== mm_core (gates path) — round-5 verified ===============
// C tile: NW*16 n-rows x 64 b-cols, K = NCH*32.  NW waves, NW*64 thr.
template<int NW, int NCH, bool BIAS, bool GATHER>
__device__ __forceinline__ void mm_core(
    unsigned char* sm,                       // [2][NW*2048+12288] LDS
    const float* __restrict__ W,
    const unsigned short* __restrict__ Ah,
    const unsigned short* __restrict__ Am,
    const unsigned short* __restrict__ Al,
    const float* __restrict__ Gsrc,          // GATHER: embed + k-col base
    const unsigned long long* __restrict__ slots_in, int tstep,
    float* __restrict__ sym_dst,             // GATHER: sym_out or nullptr
    int n0, const float* __restrict__ bias,
    float* __restrict__ out, size_t out_bstride)
{
    constexpr int NT     = NW * 64;
    constexpr int WBYTES = NW * 2048;
    constexpr int BUFSZ  = WBYTES + 12288;

    const int tid  = threadIdx.x;
    const int lane = tid & 63;
    const int wid  = tid >> 6;

    f32x4 acc[4] = {};

    const unsigned char* Wb = (const unsigned char*)W;
    const unsigned char* Apb[3] = {(const unsigned char*)Ah, (const unsigned char*)Am,
                                   (const unsigned char*)Al};

    const int ar = tid >> 2, as = tid & 3;
    const int aswz = as ^ ((ar >> 1) & 3);
    const size_t asrc_off = (size_t)ar * 2048 + (size_t)aswz * 16;
    const size_t aldst    = (size_t)ar * 64 + (size_t)aswz * 16;

    const float* grow = nullptr;
    if constexpr (GATHER) {
        if (tid < 256) {
            int symv = 1;
            if (tstep > 0) {
                unsigned long long key = slots_in[ar];   // prev-launch write: coherent
                symv = decode_key(key);
                if (sym_dst != nullptr && as == 0)
                    sym_dst[ar * Tdim + tstep] = (float)symv;
            }
            grow = Gsrc + (size_t)symv * 1024 + as * 8;
        }
    }

    auto stage = [&](int bufidx, int ch) {
        unsigned char* bb = sm + bufidx * BUFSZ;
        const size_t kb4 = (size_t)ch * 128;
#pragma unroll
        for (int s = 0; s < 2; s++) {
            int gg = tid + NT * s;
            int rw = gg >> 3, cc = gg & 7;
            int sg = cc ^ (rw & 7);
            gll16(Wb + (size_t)rw * 4096 + kb4 + (size_t)sg * 16,
                  bb + ((wid * 64 + NT * s) << 4));
        }
        if constexpr (GATHER) {
            if (tid < 256) {
                const float* p = grow + ch * 32;
                float4 f0 = *(const float4*)(p);
                float4 f1 = *(const float4*)(p + 4);
                u16x8 vh, vm, vl;
                BSplit s0 = bsplit3v(f0.x); vh[0] = s0.h; vm[0] = s0.m; vl[0] = s0.l;
                BSplit s1 = bsplit3v(f0.y); vh[1] = s1.h; vm[1] = s1.m; vl[1] = s1.l;
                BSplit s2 = bsplit3v(f0.z); vh[2] = s2.h; vm[2] = s2.m; vl[2] = s2.l;
                BSplit s3 = bsplit3v(f0.w); vh[3] = s3.h; vm[3] = s3.m; vl[3] = s3.l;
                BSplit s4 = bsplit3v(f1.x); vh[4] = s4.h; vm[4] = s4.m; vl[4] = s4.l;
                BSplit s5 = bsplit3v(f1.y); vh[5] = s5.h; vm[5] = s5.m; vl[5] = s5.l;
                BSplit s6 = bsplit3v(f1.z); vh[6] = s6.h; vm[6] = s6.m; vl[6] = s6.l;
                BSplit s7 = bsplit3v(f1.w); vh[7] = s7.h; vm[7] = s7.m; vl[7] = s7.l;
                *(u16x8*)(bb + WBYTES + aldst)        = vh;
                *(u16x8*)(bb + WBYTES + 4096 + aldst) = vm;
                *(u16x8*)(bb + WBYTES + 8192 + aldst) = vl;
            }
        } else {
            if (tid < 256) {
                const size_t kb2 = (size_t)ch * 64;
#pragma unroll
                for (int pl = 0; pl < 3; pl++)
                    gll16(Apb[pl] + asrc_off + kb2,
                          bb + WBYTES + pl * 4096 + (wid << 10));
            }
        }
    };

    stage(0, 0);
    __syncthreads();

    const int col  = lane & 15;
    const int kg   = lane >> 4;
    const int wrow = wid * 16 + col;
    const int wg0  = (2 * kg) ^ (wrow & 7);
    const int wg1  = (2 * kg + 1) ^ (wrow & 7);

#pragma unroll 2
    for (int ch = 0; ch < NCH; ch++) {
        if (ch + 1 < NCH) stage((ch + 1) & 1, ch + 1);
        unsigned char* base = sm + (ch & 1) * BUFSZ;

        const unsigned char* Wr = base + wrow * 128;
        f32x4 w0 = *(const f32x4*)(Wr + (wg0 << 4));
        f32x4 w1 = *(const f32x4*)(Wr + (wg1 << 4));
        bf16x8 whi, wmid, wlo;
#pragma unroll
        for (int j = 0; j < 4; j++) {
            float x0 = w0[j], x1 = w1[j];
            __bf16 a0 = (__bf16)x0; float r0 = x0 - (float)a0;
            __bf16 b0 = (__bf16)r0; float q0 = r0 - (float)b0;
            whi[j] = a0; wmid[j] = b0; wlo[j] = (__bf16)q0;
            __bf16 a1 = (__bf16)x1; float r1 = x1 - (float)a1;
            __bf16 b1 = (__bf16)r1; float q1 = r1 - (float)b1;
            whi[4 + j] = a1; wmid[4 + j] = b1; wlo[4 + j] = (__bf16)q1;
        }
#pragma unroll
        for (int bt = 0; bt < 4; bt++) {
            const int arow = bt * 16 + col;
            const unsigned char* Ar = base + WBYTES + arow * 64
                                    + ((kg ^ ((arow >> 1) & 3)) << 4);
            bf16x8 ahi = *(const bf16x8*)Ar;
            bf16x8 ami = *(const bf16x8*)(Ar + 4096);
            bf16x8 alo = *(const bf16x8*)(Ar + 8192);
            acc[bt] = __builtin_amdgcn_mfma_f32_16x16x32_bf16(whi,  ahi, acc[bt], 0, 0, 0);
            acc[bt] = __builtin_amdgcn_mfma_f32_16x16x32_bf16(whi,  ami, acc[bt], 0, 0, 0);
            acc[bt] = __builtin_amdgcn_mfma_f32_16x16x32_bf16(wmid, ahi, acc[bt], 0, 0, 0);
            acc[bt] = __builtin_amdgcn_mfma_f32_16x16x32_bf16(whi,  alo, acc[bt], 0, 0, 0);
            acc[bt] = __builtin_amdgcn_mfma_f32_16x16x32_bf16(wlo,  ahi, acc[bt], 0, 0, 0);
            acc[bt] = __builtin_amdgcn_mfma_f32_16x16x32_bf16(wmid, ami, acc[bt], 0, 0, 0);
        }
        __syncthreads();
    }

    const int ncol = n0 + wid * 16 + kg * 4;
    f32x4 bv = {};
    if (BIAS) bv = *(const f32x4*)(bias + ncol);

#pragma unroll
    for (int bt = 0; bt < 4; bt++) {
        const int b = bt * 16 + col;
        float* op = out + (size_t)b * out_bstride + ncol;
        f32x4 vv;
#pragma unroll
        for (int r = 0; r < 4; r++) {
            float val = acc[bt][r];
            if (BIAS) val += bv[r];
            vv[r] = val;
        }
        *(f32x4*)op = vv;
    }
}

// gates partials: gp[y*4+z][b][n] = sum_{k in z-quarter} a[y-part] . W_y[n]
// y=0 gathers x = embed[sym] straight into LDS (sym from prev k_logits launch)
// and block (0,0,0) emits sym_out[:, t].  grid (64, 2, 4) = 512 blocks, K=256.
__global__ __launch_bounds__(256, 2) void k_gates(
    const float* __restrict__ w_ih, const float* __restrict__ w_hh,
    const unsigned short* __restrict__ hh, const unsigned short* __restrict__ hm,
    const unsigned short* __restrict__ hl,
    const float* __restrict__ embed, unsigned long long* __restrict__ slots,
    int t, float* __restrict__ sym_out, float* __restrict__ gp)
{
    __shared__ __align__(16) unsigned char smem[2][20480];
    const int nbi = blockIdx.x, y = blockIdx.y, z = blockIdx.z;
    const float* W = (y ? w_hh : w_ih) + (size_t)nbi * 65536 + z * 256;
    float* gout = gp + (size_t)(y * 4 + z) * (Bdim * 4096);
    if (y)
        mm_core<4, 8, false, false>(&smem[0][0], W,
            hh + z * 256, hm + z * 256, hl + z * 256, nullptr, nullptr, t, nullptr,
            nbi * 64, nullptr, gout, 4096);
    else
        mm_core<4, 8, false, true>(&smem[0][0], W,
            nullptr, nullptr, nullptr, embed + z * 256, slots, t,
            ((nbi == 0 && z == 0) ? sym_out : nullptr),
            nbi * 64, nullptr, gout, 4096);
}

// LSTM elementwise: gates = sum of 8 partials + b_ih + b_hh (fixed order).
// Emits h as 3 bf16 planes for the next GEMMs; resets argmax slots.
__global__ void k_cell(const float* __restrict__ gp, const float* __restrict__ b_ih,
                       const float* __restrict__ b_hh, float* __restrict__ cbuf,
                       unsigned short* __restrict__ hh, unsigned short* __restrict__ hm,
                       unsigned short* __restrict__ hl,
                       unsigned long long* __restrict__ slots)
{
    const int idx = blockIdx.x * 256 + threadIdx.x;   // 0..65535
    const int b = idx >> 10, k = idx & 1023;
    const size_t S = (size_t)Bdim * 4096;
    const size_t base = (size_t)b * 4096;
    float g[4];
#pragma unroll
    for (int q = 0; q < 4; q++) {
        size_t o = base + q * 1024 + k;
        float s = gp[o];
#pragma unroll
        for (int i = 1; i < 8; i++) s += gp[i * S + o];
        g[q] = s + b_ih[q * 1024 + k] + b_hh[q * 1024 + k];
    }
    float si = 1.f / (1.f + expf(-g[0]));
    float sf = 1.f / (1.f + expf(-g[1]));
    float so = 1.f / (1.f + expf(-g[3]));
    float c  = cbuf[idx];
    float c2 = sf * c + si * tanhf(g[2]);
    float h2 = so * tanhf(c2);
    cbuf[idx] = c2;
    unsigned short hs, ms, ls;
    bsplit3(h2, hs, ms, ls);
    const size_t o = (size_t)b * 1024 + k;
    hh[o] = hs; hm[o] = ms; hl[o] = ls;
    if (idx < 64) slots[idx] = 0ull;   // reset for upcoming k_logits argmax
}

// initial state: sym[:,0] = SOS(=1), xs = split(embed[1]), h = split(h0), c = c0
__global__ void k_init(const float* __restrict__ embed, const float* __restrict__ h0,
                       const float* __restrict__ c0,
                       unsigned short* __restrict__ xsh, unsigned short* __restrict__ xsm,
                       unsigned short* __restrict__ xsl,
                       unsigned short* __restrict__ hh, unsigned short* __restrict__ hm,
                       unsigned short* __restrict__ hl,
                       float* __restrict__ cbuf, float* __restrict__ sym_out,
                       unsigned long long* __restrict__ slots)
{
    const int b = blockIdx.x, t4 = threadIdx.x * 4;
    if (threadIdx.x == 0) { sym_out[b * Tdim] = 1.0f; slots[b] = 0ull; }
    const size_t o = (size_t)b * 1024 + t4;
    ushort4 hi4, mi4, lo4;

    float4 e = *(const float4*)(embed + 1024 + t4);     // embed[SOS=1]
    bsplit3(e.x, hi4.x, mi4.x, lo4.x);
    bsplit3(e.y, hi4.y, mi4.y, lo4.y);
    bsplit3(e.z, hi4.z, mi4.z, lo4.z);
    bsplit3(e.w, hi4.w, mi4.w, lo4.w);
    *(ushort4*)(xsh + o) = hi4; *(ushort4*)(xsm + o) = mi4; *(ushort4*)(xsl + o) = lo4;

    float4 hv = *(const float4*)(h0 + (size_t)b * 1024 + t4);
    bsplit3(hv.x, hi4.x, mi4.x, lo4.x);
    bsplit3(hv.y, hi4.y, mi4.y, lo4.y);
    bsplit3(hv.z, hi4.z, mi4.z, lo4.z);
    bsplit3(hv.w, hi4.w, mi4.w, lo4.w);
    *(ushort4*)(hh + o) = hi4; *(ushort4*)(hm + o) = mi4; *(ushort4*)(hl + o) = lo4;

    float4 cv = *(const float4*)(c0 + (size_t)b * 1024 + t4);
    *(float4*)(cbuf + (size_t)b * 1024 + t4) = cv;
}

// final symbol from the last k_logits' slots (kernel-boundary coherent)
__global__ void k_symfinal(const unsigned long long* __restrict__ slots,
                           float* __restrict__ sym_out)
{
    const int b = threadIdx.x;
    sym_out[b * Tdim + (Tdim - 1)] = (float)decode_key(slots[b]);
}

extern "C" void kernel_launch(void* const* d_in, const int* in_sizes, int n_in,
                              void* d_out, int out_size, void* d_ws, size_t ws_size,
                              hipStream_t stream)
{
    // setup_inputs order:
    // 0 output (unused), 1 h0, 2 c0, 3 target_outputs (unused), 4 target_lengths (unused),
    // 5 embed, 6 w_ih, 7 w_hh, 8 b_ih, 9 b_hh, 10 w_out, 11 b_out
    const float* h0    = (const float*)d_in[1];
    const float* c0    = (const float*)d_in[2];
    const float* embed = (const float*)d_in[5];
    const float* w_ih  = (const float*)d_in[6];
    const float* w_hh  = (const float*)d_in[7];
    const float* b_ih  = (const float*)d_in[8];
    const float* b_hh  = (const float*)d_in[9];
    const float* w_out = (const float*)d_in[10];
    const float* b_out = (const float*)d_in[11];

    float* out = (float*)d_out;                       // [B][T][V] then [B][T] symbols (as f32)
    float* sym_out = out + (size_t)Bdim * Tdim * Vdim;

    // workspace (~9.4 MB): h planes + SOS-x planes (each [64][1024] u16),
    // cbuf [64][1024] f32, gp [8][64][4096] f32 partials, slots[64]
    unsigned short* hh  = (unsigned short*)d_ws;
    unsigned short* hm  = hh + (size_t)Bdim * 1024;
    unsigned short* hl  = hm + (size_t)Bdim * 1024;
    unsigned short* xsh = hl + (size_t)Bdim * 1024;
    unsigned short* xsm = xsh + (size_t)Bdim * 1024;
    unsigned short* xsl = xsm + (size_t)Bdim * 1024;
    float* cbuf = (float*)(xsl + (size_t)Bdim * 1024);
    float* gp   = cbuf + (size_t)Bdim * Hdim;
    unsigned long long* slots = (unsigned long long*)(gp + 8ull * Bdim * 4096);

    k_init<<<Bdim, 256, 0, stream>>>(embed, h0, c0, xsh, xsm, xsl,
                                     hh, hm, hl, cbuf, sym_out, slots);

    // decs[0] = embed[SOS] @ w_out.T + b_out (no argmax)
    k_logits<false><<<Vdim / 128, 512, 0, stream>>>(w_out, xsh, xsm, xsl,
                                                    b_out, out, slots);

    for (int t = 0; t < Tdim - 1; t++) {
        k_gates<<<dim3(64, 2, 4), 256, 0, stream>>>(w_ih, w_hh, hh, hm, hl,
                                                    embed, slots, t, sym_out, gp);
        k_cell<<<Bdim * Hdim / 256, 256, 0, stream>>>(gp, b_ih, b_hh, cbuf,
                                                      hh, hm, hl, slots);
        k_logits<true><<<Vdim / 128, 512, 0, stream>>>(w_out, hh, hm, hl,
                                                       b_out, out + (size_t)(t + 1) * Vdim,
                                                       slots);
    }
    k_symfinal<<<1, 64, 0, stream>>>(slots, sym_out);
}

// Round 8
// 2298.479 us; speedup vs baseline: 2.3602x; 2.3602x over previous
//
#include <hip/hip_runtime.h>

#define Bdim 64
#define Hdim 1024
#define Vdim 32000
#define Tdim 40

typedef __bf16 bf16x8 __attribute__((ext_vector_type(8)));
typedef float  f32x4  __attribute__((ext_vector_type(4)));
typedef unsigned short u16x8 __attribute__((ext_vector_type(8)));
static_assert(sizeof(bf16x8) == 16, "bf16x8 must be 16B");

// Order-preserving float->uint32 map; pack with (0xFFFFFFFF - v) so that
// u64 max == (max value, lowest index on exact ties) — matches np.argmax.
__device__ __forceinline__ unsigned long long pack_key(float f, int v) {
    unsigned u = __float_as_uint(f);
    u = (u & 0x80000000u) ? ~u : (u | 0x80000000u);
    return ((unsigned long long)u << 32) | (unsigned long long)(0xFFFFFFFFu - (unsigned)v);
}

__device__ __forceinline__ int decode_key(unsigned long long key) {
    return (int)(0xFFFFFFFFu - (unsigned)(key & 0xFFFFFFFFull));
}

__device__ __forceinline__ void gll16(const void* g, void* l) {
    __builtin_amdgcn_global_load_lds(
        (const __attribute__((address_space(1))) void*)g,
        (__attribute__((address_space(3))) void*)l, 16, 0, 0);
}

struct BSplit2 { unsigned short h, m; };

// f32 -> bf16 hi/mid (~17-bit effective mantissa; residual ~2^-18 relative).
// Error budget: logits abs err ~6e-6 vs argmax top-2 gap ~0.2 and decs
// threshold floor 3.9e-3 — 3 orders of margin (round-8 analysis).
__device__ __forceinline__ BSplit2 bsplit2v(float x) {
    __bf16 h = (__bf16)x;  float r = x - (float)h;
    __bf16 m = (__bf16)r;
    BSplit2 s;
    s.h = __builtin_bit_cast(unsigned short, h);
    s.m = __builtin_bit_cast(unsigned short, m);
    return s;
}

__device__ __forceinline__ void bsplit2(float x, unsigned short& a, unsigned short& b) {
    BSplit2 s = bsplit2v(x);
    a = s.h; b = s.m;
}

// C tile: NW*16 n-rows (W rows) x 64 b-cols, K = NCH*32.  NW waves, NW*64 thr.
// W: f32 [NW*16][K], row stride 1024 f32, split to bf16 hi/mid on the fly.
// A: either 2 pre-split bf16 planes ([64][1024] u16) staged via gll16 with
//    pre-swizzled source, or (GATHER) f32 rows gathered from embed[sym[b]]
//    (sym from the PREVIOUS k_logits launch — kernel-boundary coherence),
//    split in-register and ds_written to the SAME swizzled layout (rule #21).
// 3-pass bf16x2 product (hh + hm + mh) => ~2^-17-relative accuracy; argmax
// trajectory matches f32 (margin analysis above).
// MFMA 16x16x32 layouts: A/B frag = 8 contiguous k at row lane&15, kgroup lane>>4;
// C/D: col=lane&15 (b), row=(lane>>4)*4+reg (n). Verified per learn_hip m89/m92;
// structure is the round-5 harness-verified code (2606us), planes 3->2.
template<int NW, int NCH, bool ARGMAX, bool BIAS, bool GATHER>
__device__ __forceinline__ void mm_core(
    unsigned char* sm,                       // [2][NW*2048+8192] LDS
    unsigned long long (*red)[4][16],        // [NW][4][16] LDS (ARGMAX only)
    const float* __restrict__ W,
    const unsigned short* __restrict__ Ah,
    const unsigned short* __restrict__ Am,
    const float* __restrict__ Gsrc,          // GATHER: embed + k-col base
    const unsigned long long* __restrict__ slots_in, int tstep,
    float* __restrict__ sym_dst,             // GATHER: sym_out or nullptr
    int n0, const float* __restrict__ bias,
    float* __restrict__ out, size_t out_bstride,
    unsigned long long* __restrict__ slots_out)
{
    constexpr int NT     = NW * 64;          // threads
    constexpr int WBYTES = NW * 2048;        // W tile bytes/chunk (NW*16 rows x 128B)
    constexpr int BUFSZ  = WBYTES + 8192;    // + 2 A planes x 4096 B

    const int tid  = threadIdx.x;
    const int lane = tid & 63;
    const int wid  = tid >> 6;

    f32x4 acc[4] = {};

    const unsigned char* Wb = (const unsigned char*)W;
    const unsigned char* Apb[2] = {(const unsigned char*)Ah, (const unsigned char*)Am};

    // A staging: 256 granules/plane-chunk (64 rows x 4x16B), threads 0..255 only
    const int ar = tid >> 2, as = tid & 3;
    const int aswz = as ^ ((ar >> 1) & 3);
    const size_t asrc_off = (size_t)ar * 2048 + (size_t)aswz * 16;  // [64][1024]u16 rows
    const size_t aldst    = (size_t)ar * 64 + (size_t)aswz * 16;    // swizzled LDS pos

    const float* grow = nullptr;
    if constexpr (GATHER) {
        if (tid < 256) {
            int symv = 1;
            if (tstep > 0) {
                unsigned long long key = slots_in[ar];   // prev-launch write: coherent
                symv = decode_key(key);
                if (sym_dst != nullptr && as == 0)
                    sym_dst[ar * Tdim + tstep] = (float)symv;
            }
            grow = Gsrc + (size_t)symv * 1024 + as * 8;
        }
    }

    auto stage = [&](int bufidx, int ch) {
        unsigned char* bb = sm + bufidx * BUFSZ;
        const size_t kb4 = (size_t)ch * 128;  // 32 f32 = 128 B
        // W: NW*128 granules (NW*16 rows x 8x16B), 2/thread, swizzle g^(row&7)
#pragma unroll
        for (int s = 0; s < 2; s++) {
            int gg = tid + NT * s;
            int rw = gg >> 3, cc = gg & 7;
            int sg = cc ^ (rw & 7);
            gll16(Wb + (size_t)rw * 4096 + kb4 + (size_t)sg * 16,
                  bb + ((wid * 64 + NT * s) << 4));
        }
        if constexpr (GATHER) {
            if (tid < 256) {
                const float* p = grow + ch * 32;
                float4 f0 = *(const float4*)(p);
                float4 f1 = *(const float4*)(p + 4);
                u16x8 vh, vm;
                BSplit2 s0 = bsplit2v(f0.x); vh[0] = s0.h; vm[0] = s0.m;
                BSplit2 s1 = bsplit2v(f0.y); vh[1] = s1.h; vm[1] = s1.m;
                BSplit2 s2 = bsplit2v(f0.z); vh[2] = s2.h; vm[2] = s2.m;
                BSplit2 s3 = bsplit2v(f0.w); vh[3] = s3.h; vm[3] = s3.m;
                BSplit2 s4 = bsplit2v(f1.x); vh[4] = s4.h; vm[4] = s4.m;
                BSplit2 s5 = bsplit2v(f1.y); vh[5] = s5.h; vm[5] = s5.m;
                BSplit2 s6 = bsplit2v(f1.z); vh[6] = s6.h; vm[6] = s6.m;
                BSplit2 s7 = bsplit2v(f1.w); vh[7] = s7.h; vm[7] = s7.m;
                *(u16x8*)(bb + WBYTES + aldst)        = vh;
                *(u16x8*)(bb + WBYTES + 4096 + aldst) = vm;
            }
        } else {
            if (tid < 256) {
                const size_t kb2 = (size_t)ch * 64;   // 32 bf16 = 64 B
#pragma unroll
                for (int pl = 0; pl < 2; pl++)
                    gll16(Apb[pl] + asrc_off + kb2,
                          bb + WBYTES + pl * 4096 + (wid << 10));
            }
        }
    };

    stage(0, 0);
    __syncthreads();

    const int col  = lane & 15;
    const int kg   = lane >> 4;
    const int wrow = wid * 16 + col;          // this wave's n-row within tile
    const int wg0  = (2 * kg) ^ (wrow & 7);
    const int wg1  = (2 * kg + 1) ^ (wrow & 7);

#pragma unroll 2
    for (int ch = 0; ch < NCH; ch++) {
        if (ch + 1 < NCH) stage((ch + 1) & 1, ch + 1);   // async prefetch next chunk
        unsigned char* base = sm + (ch & 1) * BUFSZ;

        // W fragment: 8 contiguous f32 at row wrow (two swizzled 16B reads),
        // split to hi/mid (3 VALU ops per f32)
        const unsigned char* Wr = base + wrow * 128;
        f32x4 w0 = *(const f32x4*)(Wr + (wg0 << 4));
        f32x4 w1 = *(const f32x4*)(Wr + (wg1 << 4));
        bf16x8 whi, wmid;
#pragma unroll
        for (int j = 0; j < 4; j++) {
            float x0 = w0[j], x1 = w1[j];
            __bf16 a0 = (__bf16)x0; float r0 = x0 - (float)a0;
            whi[j] = a0; wmid[j] = (__bf16)r0;
            __bf16 a1 = (__bf16)x1; float r1 = x1 - (float)a1;
            whi[4 + j] = a1; wmid[4 + j] = (__bf16)r1;
        }
#pragma unroll
        for (int bt = 0; bt < 4; bt++) {
            const int arow = bt * 16 + col;
            const unsigned char* Ar = base + WBYTES + arow * 64
                                    + ((kg ^ ((arow >> 1) & 3)) << 4);
            bf16x8 ahi = *(const bf16x8*)Ar;
            bf16x8 ami = *(const bf16x8*)(Ar + 4096);
            acc[bt] = __builtin_amdgcn_mfma_f32_16x16x32_bf16(whi,  ahi, acc[bt], 0, 0, 0);
            acc[bt] = __builtin_amdgcn_mfma_f32_16x16x32_bf16(whi,  ami, acc[bt], 0, 0, 0);
            acc[bt] = __builtin_amdgcn_mfma_f32_16x16x32_bf16(wmid, ahi, acc[bt], 0, 0, 0);
        }
        __syncthreads();
    }

    // epilogue: bias add, f32x4 store, block argmax
    const int ncol = n0 + wid * 16 + kg * 4;   // absolute n for 4 acc regs
    f32x4 bv = {};
    if (BIAS) bv = *(const f32x4*)(bias + ncol);

    unsigned long long bk[4];
#pragma unroll
    for (int bt = 0; bt < 4; bt++) {
        const int b = bt * 16 + col;
        float* op = out + (size_t)b * out_bstride + ncol;
        f32x4 vv;
        unsigned long long best = 0ull;
#pragma unroll
        for (int r = 0; r < 4; r++) {
            float val = acc[bt][r];
            if (BIAS) val += bv[r];
            vv[r] = val;
            if (ARGMAX) {
                unsigned long long key = pack_key(val, ncol + r);
                if (key > best) best = key;
            }
        }
        *(f32x4*)op = vv;
        bk[bt] = best;
    }

    if constexpr (ARGMAX) {
#pragma unroll
        for (int bt = 0; bt < 4; bt++) {
            unsigned long long k = bk[bt];
            unsigned long long o = __shfl_xor(k, 16, 64); if (o > k) k = o;
            o = __shfl_xor(k, 32, 64);                    if (o > k) k = o;
            if (lane < 16) red[wid][bt][lane] = k;
        }
        __syncthreads();
        if (tid < 64) {
            const int bt = tid >> 4, c = tid & 15;
            unsigned long long k = red[0][bt][c];
#pragma unroll
            for (int w = 1; w < NW; w++)
                if (red[w][bt][c] > k) k = red[w][bt][c];
            atomicMax(&slots_out[bt * 16 + c], k);
        }
    }
}

// logits: C[v][b] = h . w_out[v] + b_out[v]; grid 250 x (128v x 64b), 512 thr
template<bool AM>
__global__ __launch_bounds__(512, 1) void k_logits(
    const float* __restrict__ w_out,
    const unsigned short* __restrict__ ah, const unsigned short* __restrict__ am,
    const float* __restrict__ b_out, float* __restrict__ out,
    unsigned long long* __restrict__ slots)
{
    __shared__ __align__(16) unsigned char smem[2][24576];
    __shared__ unsigned long long red[8][4][16];
    const int vb = blockIdx.x * 128;
    mm_core<8, 32, AM, true, false>(&smem[0][0], red,
        w_out + (size_t)vb * Hdim, ah, am, nullptr, nullptr, 0, nullptr,
        vb, b_out, out, (size_t)Tdim * Vdim, slots);
}

// gates partials: gp[y*4+z][b][n] = sum_{k in z-quarter} a[y-part] . W_y[n]
// y=0 gathers x = embed[sym] straight into LDS (sym from prev k_logits launch)
// and block (0,0,0) emits sym_out[:, t].  grid (64, 2, 4) = 512 blocks, K=256.
__global__ __launch_bounds__(256, 2) void k_gates(
    const float* __restrict__ w_ih, const float* __restrict__ w_hh,
    const unsigned short* __restrict__ hh, const unsigned short* __restrict__ hm,
    const float* __restrict__ embed, unsigned long long* __restrict__ slots,
    int t, float* __restrict__ sym_out, float* __restrict__ gp)
{
    __shared__ __align__(16) unsigned char smem[2][16384];
    const int nbi = blockIdx.x, y = blockIdx.y, z = blockIdx.z;
    const float* W = (y ? w_hh : w_ih) + (size_t)nbi * 65536 + z * 256;
    float* gout = gp + (size_t)(y * 4 + z) * (Bdim * 4096);
    if (y)
        mm_core<4, 8, false, false, false>(&smem[0][0], nullptr, W,
            hh + z * 256, hm + z * 256, nullptr, nullptr, t, nullptr,
            nbi * 64, nullptr, gout, 4096, nullptr);
    else
        mm_core<4, 8, false, false, true>(&smem[0][0], nullptr, W,
            nullptr, nullptr, embed + z * 256, slots, t,
            ((nbi == 0 && z == 0) ? sym_out : nullptr),
            nbi * 64, nullptr, gout, 4096, nullptr);
}

// LSTM elementwise: gates = sum of 8 partials + b_ih + b_hh (fixed order).
// Emits h as 2 bf16 planes for the next GEMMs; resets argmax slots.
__global__ void k_cell(const float* __restrict__ gp, const float* __restrict__ b_ih,
                       const float* __restrict__ b_hh, float* __restrict__ cbuf,
                       unsigned short* __restrict__ hh, unsigned short* __restrict__ hm,
                       unsigned long long* __restrict__ slots)
{
    const int idx = blockIdx.x * 256 + threadIdx.x;   // 0..65535
    const int b = idx >> 10, k = idx & 1023;
    const size_t S = (size_t)Bdim * 4096;
    const size_t base = (size_t)b * 4096;
    float g[4];
#pragma unroll
    for (int q = 0; q < 4; q++) {
        size_t o = base + q * 1024 + k;
        float s = gp[o];
#pragma unroll
        for (int i = 1; i < 8; i++) s += gp[i * S + o];
        g[q] = s + b_ih[q * 1024 + k] + b_hh[q * 1024 + k];
    }
    float si = 1.f / (1.f + expf(-g[0]));
    float sf = 1.f / (1.f + expf(-g[1]));
    float so = 1.f / (1.f + expf(-g[3]));
    float c  = cbuf[idx];
    float c2 = sf * c + si * tanhf(g[2]);
    float h2 = so * tanhf(c2);
    cbuf[idx] = c2;
    unsigned short hs, ms;
    bsplit2(h2, hs, ms);
    const size_t o = (size_t)b * 1024 + k;
    hh[o] = hs; hm[o] = ms;
    if (idx < 64) slots[idx] = 0ull;   // reset for upcoming k_logits argmax
}

// initial state: sym[:,0] = SOS(=1), xs = split(embed[1]), h = split(h0), c = c0
__global__ void k_init(const float* __restrict__ embed, const float* __restrict__ h0,
                       const float* __restrict__ c0,
                       unsigned short* __restrict__ xsh, unsigned short* __restrict__ xsm,
                       unsigned short* __restrict__ hh, unsigned short* __restrict__ hm,
                       float* __restrict__ cbuf, float* __restrict__ sym_out,
                       unsigned long long* __restrict__ slots)
{
    const int b = blockIdx.x, t4 = threadIdx.x * 4;
    if (threadIdx.x == 0) { sym_out[b * Tdim] = 1.0f; slots[b] = 0ull; }
    const size_t o = (size_t)b * 1024 + t4;
    ushort4 hi4, mi4;

    float4 e = *(const float4*)(embed + 1024 + t4);     // embed[SOS=1]
    bsplit2(e.x, hi4.x, mi4.x);
    bsplit2(e.y, hi4.y, mi4.y);
    bsplit2(e.z, hi4.z, mi4.z);
    bsplit2(e.w, hi4.w, mi4.w);
    *(ushort4*)(xsh + o) = hi4; *(ushort4*)(xsm + o) = mi4;

    float4 hv = *(const float4*)(h0 + (size_t)b * 1024 + t4);
    bsplit2(hv.x, hi4.x, mi4.x);
    bsplit2(hv.y, hi4.y, mi4.y);
    bsplit2(hv.z, hi4.z, mi4.z);
    bsplit2(hv.w, hi4.w, mi4.w);
    *(ushort4*)(hh + o) = hi4; *(ushort4*)(hm + o) = mi4;

    float4 cv = *(const float4*)(c0 + (size_t)b * 1024 + t4);
    *(float4*)(cbuf + (size_t)b * 1024 + t4) = cv;
}

// final symbol from the last k_logits' slots (kernel-boundary coherent)
__global__ void k_symfinal(const unsigned long long* __restrict__ slots,
                           float* __restrict__ sym_out)
{
    const int b = threadIdx.x;
    sym_out[b * Tdim + (Tdim - 1)] = (float)decode_key(slots[b]);
}

extern "C" void kernel_launch(void* const* d_in, const int* in_sizes, int n_in,
                              void* d_out, int out_size, void* d_ws, size_t ws_size,
                              hipStream_t stream)
{
    // setup_inputs order:
    // 0 output (unused), 1 h0, 2 c0, 3 target_outputs (unused), 4 target_lengths (unused),
    // 5 embed, 6 w_ih, 7 w_hh, 8 b_ih, 9 b_hh, 10 w_out, 11 b_out
    const float* h0    = (const float*)d_in[1];
    const float* c0    = (const float*)d_in[2];
    const float* embed = (const float*)d_in[5];
    const float* w_ih  = (const float*)d_in[6];
    const float* w_hh  = (const float*)d_in[7];
    const float* b_ih  = (const float*)d_in[8];
    const float* b_hh  = (const float*)d_in[9];
    const float* w_out = (const float*)d_in[10];
    const float* b_out = (const float*)d_in[11];

    float* out = (float*)d_out;                       // [B][T][V] then [B][T] symbols (as f32)
    float* sym_out = out + (size_t)Bdim * Tdim * Vdim;

    // workspace (~9 MB): h planes + SOS-x planes (each [64][1024] u16),
    // cbuf [64][1024] f32, gp [8][64][4096] f32 partials, slots[64]
    unsigned short* hh  = (unsigned short*)d_ws;
    unsigned short* hm  = hh + (size_t)Bdim * 1024;
    unsigned short* xsh = hm + (size_t)Bdim * 1024;
    unsigned short* xsm = xsh + (size_t)Bdim * 1024;
    float* cbuf = (float*)(xsm + (size_t)Bdim * 1024);
    float* gp   = cbuf + (size_t)Bdim * Hdim;
    unsigned long long* slots = (unsigned long long*)(gp + 8ull * Bdim * 4096);

    k_init<<<Bdim, 256, 0, stream>>>(embed, h0, c0, xsh, xsm,
                                     hh, hm, cbuf, sym_out, slots);

    // decs[0] = embed[SOS] @ w_out.T + b_out (no argmax)
    k_logits<false><<<Vdim / 128, 512, 0, stream>>>(w_out, xsh, xsm,
                                                    b_out, out, slots);

    for (int t = 0; t < Tdim - 1; t++) {
        k_gates<<<dim3(64, 2, 4), 256, 0, stream>>>(w_ih, w_hh, hh, hm,
                                                    embed, slots, t, sym_out, gp);
        k_cell<<<Bdim * Hdim / 256, 256, 0, stream>>>(gp, b_ih, b_hh, cbuf,
                                                      hh, hm, slots);
        k_logits<true><<<Vdim / 128, 512, 0, stream>>>(w_out, hh, hm,
                                                       b_out, out + (size_t)(t + 1) * Vdim,
                                                       slots);
    }
    k_symfinal<<<1, 64, 0, stream>>>(slots, sym_out);
}

// Round 9
// 2267.985 us; speedup vs baseline: 2.3919x; 1.0134x over previous
//
#include <hip/hip_runtime.h>

#define Bdim 64
#define Hdim 1024
#define Vdim 32000
#define Tdim 40

typedef __bf16 bf16x8 __attribute__((ext_vector_type(8)));
typedef float  f32x4  __attribute__((ext_vector_type(4)));
typedef unsigned short u16x8 __attribute__((ext_vector_type(8)));
static_assert(sizeof(bf16x8) == 16, "bf16x8 must be 16B");

// Order-preserving float->uint32 map; pack with (0xFFFFFFFF - v) so that
// u64 max == (max value, lowest index on exact ties) — matches np.argmax.
__device__ __forceinline__ unsigned long long pack_key(float f, int v) {
    unsigned u = __float_as_uint(f);
    u = (u & 0x80000000u) ? ~u : (u | 0x80000000u);
    return ((unsigned long long)u << 32) | (unsigned long long)(0xFFFFFFFFu - (unsigned)v);
}

__device__ __forceinline__ int decode_key(unsigned long long key) {
    return (int)(0xFFFFFFFFu - (unsigned)(key & 0xFFFFFFFFull));
}

__device__ __forceinline__ void gll16(const void* g, void* l) {
    __builtin_amdgcn_global_load_lds(
        (const __attribute__((address_space(1))) void*)g,
        (__attribute__((address_space(3))) void*)l, 16, 0, 0);
}

struct BSplit2 { unsigned short h, m; };

// f32 -> bf16 hi/mid (~17-bit effective mantissa; residual ~2^-18 relative).
// Error budget: logits abs err ~6e-6 vs argmax top-2 gap ~0.2 and decs
// threshold floor — 3 orders of margin (round-8: passed, absmax 0.0078).
__device__ __forceinline__ BSplit2 bsplit2v(float x) {
    __bf16 h = (__bf16)x;  float r = x - (float)h;
    __bf16 m = (__bf16)r;
    BSplit2 s;
    s.h = __builtin_bit_cast(unsigned short, h);
    s.m = __builtin_bit_cast(unsigned short, m);
    return s;
}

__device__ __forceinline__ void bsplit2(float x, unsigned short& a, unsigned short& b) {
    BSplit2 s = bsplit2v(x);
    a = s.h; b = s.m;
}

// C tile: NW*16 n-rows (W rows) x 64 b-cols, K = NCH*32.  NW waves, NW*64 thr.
// W: f32 [NW*16][K], row stride 1024 f32, split to bf16 hi/mid on the fly.
// A: either 2 pre-split bf16 planes ([64][1024] u16) staged via gll16 with
//    pre-swizzled source, or (GATHER) f32 rows gathered from embed[sym[b]]
//    (sym from the PREVIOUS k_logits launch — kernel-boundary coherence),
//    split in-register and ds_written to the SAME swizzled layout (rule #21).
// 3-pass bf16x2 product (hh + hm + mh) => ~2^-17-relative accuracy; argmax
// trajectory matches f32 (margin analysis above; round-8 harness-verified).
// NTST: non-temporal C-store — the 328 MB/invocation decs stream is
// write-once, and letting it allocate L3 evicts the 131 MB w_out that the
// next 39 logits dispatches re-read (round-9 theory: keep w_out L3-resident).
// MFMA 16x16x32 layouts: A/B frag = 8 contiguous k at row lane&15, kgroup lane>>4;
// C/D: col=lane&15 (b), row=(lane>>4)*4+reg (n). Verified per learn_hip m89/m92.
template<int NW, int NCH, bool ARGMAX, bool BIAS, bool GATHER, bool NTST>
__device__ __forceinline__ void mm_core(
    unsigned char* sm,                       // [2][NW*2048+8192] LDS
    unsigned long long (*red)[4][16],        // [NW][4][16] LDS (ARGMAX only)
    const float* __restrict__ W,
    const unsigned short* __restrict__ Ah,
    const unsigned short* __restrict__ Am,
    const float* __restrict__ Gsrc,          // GATHER: embed + k-col base
    const unsigned long long* __restrict__ slots_in, int tstep,
    float* __restrict__ sym_dst,             // GATHER: sym_out or nullptr
    int n0, const float* __restrict__ bias,
    float* __restrict__ out, size_t out_bstride,
    unsigned long long* __restrict__ slots_out)
{
    constexpr int NT     = NW * 64;          // threads
    constexpr int WBYTES = NW * 2048;        // W tile bytes/chunk (NW*16 rows x 128B)
    constexpr int BUFSZ  = WBYTES + 8192;    // + 2 A planes x 4096 B

    const int tid  = threadIdx.x;
    const int lane = tid & 63;
    const int wid  = tid >> 6;

    f32x4 acc[4] = {};

    const unsigned char* Wb = (const unsigned char*)W;
    const unsigned char* Apb[2] = {(const unsigned char*)Ah, (const unsigned char*)Am};

    // A staging: 256 granules/plane-chunk (64 rows x 4x16B), threads 0..255 only
    const int ar = tid >> 2, as = tid & 3;
    const int aswz = as ^ ((ar >> 1) & 3);
    const size_t asrc_off = (size_t)ar * 2048 + (size_t)aswz * 16;  // [64][1024]u16 rows
    const size_t aldst    = (size_t)ar * 64 + (size_t)aswz * 16;    // swizzled LDS pos

    const float* grow = nullptr;
    if constexpr (GATHER) {
        if (tid < 256) {
            int symv = 1;
            if (tstep > 0) {
                unsigned long long key = slots_in[ar];   // prev-launch write: coherent
                symv = decode_key(key);
                if (sym_dst != nullptr && as == 0)
                    sym_dst[ar * Tdim + tstep] = (float)symv;
            }
            grow = Gsrc + (size_t)symv * 1024 + as * 8;
        }
    }

    auto stage = [&](int bufidx, int ch) {
        unsigned char* bb = sm + bufidx * BUFSZ;
        const size_t kb4 = (size_t)ch * 128;  // 32 f32 = 128 B
        // W: NW*128 granules (NW*16 rows x 8x16B), 2/thread, swizzle g^(row&7)
#pragma unroll
        for (int s = 0; s < 2; s++) {
            int gg = tid + NT * s;
            int rw = gg >> 3, cc = gg & 7;
            int sg = cc ^ (rw & 7);
            gll16(Wb + (size_t)rw * 4096 + kb4 + (size_t)sg * 16,
                  bb + ((wid * 64 + NT * s) << 4));
        }
        if constexpr (GATHER) {
            if (tid < 256) {
                const float* p = grow + ch * 32;
                float4 f0 = *(const float4*)(p);
                float4 f1 = *(const float4*)(p + 4);
                u16x8 vh, vm;
                BSplit2 s0 = bsplit2v(f0.x); vh[0] = s0.h; vm[0] = s0.m;
                BSplit2 s1 = bsplit2v(f0.y); vh[1] = s1.h; vm[1] = s1.m;
                BSplit2 s2 = bsplit2v(f0.z); vh[2] = s2.h; vm[2] = s2.m;
                BSplit2 s3 = bsplit2v(f0.w); vh[3] = s3.h; vm[3] = s3.m;
                BSplit2 s4 = bsplit2v(f1.x); vh[4] = s4.h; vm[4] = s4.m;
                BSplit2 s5 = bsplit2v(f1.y); vh[5] = s5.h; vm[5] = s5.m;
                BSplit2 s6 = bsplit2v(f1.z); vh[6] = s6.h; vm[6] = s6.m;
                BSplit2 s7 = bsplit2v(f1.w); vh[7] = s7.h; vm[7] = s7.m;
                *(u16x8*)(bb + WBYTES + aldst)        = vh;
                *(u16x8*)(bb + WBYTES + 4096 + aldst) = vm;
            }
        } else {
            if (tid < 256) {
                const size_t kb2 = (size_t)ch * 64;   // 32 bf16 = 64 B
#pragma unroll
                for (int pl = 0; pl < 2; pl++)
                    gll16(Apb[pl] + asrc_off + kb2,
                          bb + WBYTES + pl * 4096 + (wid << 10));
            }
        }
    };

    stage(0, 0);
    __syncthreads();

    const int col  = lane & 15;
    const int kg   = lane >> 4;
    const int wrow = wid * 16 + col;          // this wave's n-row within tile
    const int wg0  = (2 * kg) ^ (wrow & 7);
    const int wg1  = (2 * kg + 1) ^ (wrow & 7);

#pragma unroll 2
    for (int ch = 0; ch < NCH; ch++) {
        if (ch + 1 < NCH) stage((ch + 1) & 1, ch + 1);   // async prefetch next chunk
        unsigned char* base = sm + (ch & 1) * BUFSZ;

        // W fragment: 8 contiguous f32 at row wrow (two swizzled 16B reads),
        // split to hi/mid (3 VALU ops per f32)
        const unsigned char* Wr = base + wrow * 128;
        f32x4 w0 = *(const f32x4*)(Wr + (wg0 << 4));
        f32x4 w1 = *(const f32x4*)(Wr + (wg1 << 4));
        bf16x8 whi, wmid;
#pragma unroll
        for (int j = 0; j < 4; j++) {
            float x0 = w0[j], x1 = w1[j];
            __bf16 a0 = (__bf16)x0; float r0 = x0 - (float)a0;
            whi[j] = a0; wmid[j] = (__bf16)r0;
            __bf16 a1 = (__bf16)x1; float r1 = x1 - (float)a1;
            whi[4 + j] = a1; wmid[4 + j] = (__bf16)r1;
        }
#pragma unroll
        for (int bt = 0; bt < 4; bt++) {
            const int arow = bt * 16 + col;
            const unsigned char* Ar = base + WBYTES + arow * 64
                                    + ((kg ^ ((arow >> 1) & 3)) << 4);
            bf16x8 ahi = *(const bf16x8*)Ar;
            bf16x8 ami = *(const bf16x8*)(Ar + 4096);
            acc[bt] = __builtin_amdgcn_mfma_f32_16x16x32_bf16(whi,  ahi, acc[bt], 0, 0, 0);
            acc[bt] = __builtin_amdgcn_mfma_f32_16x16x32_bf16(whi,  ami, acc[bt], 0, 0, 0);
            acc[bt] = __builtin_amdgcn_mfma_f32_16x16x32_bf16(wmid, ahi, acc[bt], 0, 0, 0);
        }
        __syncthreads();
    }

    // epilogue: bias add, f32x4 store (nt for write-once logits), block argmax
    const int ncol = n0 + wid * 16 + kg * 4;   // absolute n for 4 acc regs
    f32x4 bv = {};
    if (BIAS) bv = *(const f32x4*)(bias + ncol);

    unsigned long long bk[4];
#pragma unroll
    for (int bt = 0; bt < 4; bt++) {
        const int b = bt * 16 + col;
        float* op = out + (size_t)b * out_bstride + ncol;
        f32x4 vv;
        unsigned long long best = 0ull;
#pragma unroll
        for (int r = 0; r < 4; r++) {
            float val = acc[bt][r];
            if (BIAS) val += bv[r];
            vv[r] = val;
            if (ARGMAX) {
                unsigned long long key = pack_key(val, ncol + r);
                if (key > best) best = key;
            }
        }
        if constexpr (NTST)
            __builtin_nontemporal_store(vv, (f32x4*)op);
        else
            *(f32x4*)op = vv;
        bk[bt] = best;
    }

    if constexpr (ARGMAX) {
#pragma unroll
        for (int bt = 0; bt < 4; bt++) {
            unsigned long long k = bk[bt];
            unsigned long long o = __shfl_xor(k, 16, 64); if (o > k) k = o;
            o = __shfl_xor(k, 32, 64);                    if (o > k) k = o;
            if (lane < 16) red[wid][bt][lane] = k;
        }
        __syncthreads();
        if (tid < 64) {
            const int bt = tid >> 4, c = tid & 15;
            unsigned long long k = red[0][bt][c];
#pragma unroll
            for (int w = 1; w < NW; w++)
                if (red[w][bt][c] > k) k = red[w][bt][c];
            atomicMax(&slots_out[bt * 16 + c], k);
        }
    }
}

// logits: C[v][b] = h . w_out[v] + b_out[v]; grid 250 x (128v x 64b), 512 thr
template<bool AM>
__global__ __launch_bounds__(512, 1) void k_logits(
    const float* __restrict__ w_out,
    const unsigned short* __restrict__ ah, const unsigned short* __restrict__ am,
    const float* __restrict__ b_out, float* __restrict__ out,
    unsigned long long* __restrict__ slots)
{
    __shared__ __align__(16) unsigned char smem[2][24576];
    __shared__ unsigned long long red[8][4][16];
    const int vb = blockIdx.x * 128;
    mm_core<8, 32, AM, true, false, true>(&smem[0][0], red,
        w_out + (size_t)vb * Hdim, ah, am, nullptr, nullptr, 0, nullptr,
        vb, b_out, out, (size_t)Tdim * Vdim, slots);
}

// gates partials: gp[y*4+z][b][n] = sum_{k in z-quarter} a[y-part] . W_y[n]
// y=0 gathers x = embed[sym] straight into LDS (sym from prev k_logits launch)
// and block (0,0,0) emits sym_out[:, t].  grid (64, 2, 4) = 512 blocks, K=256.
// gp stores stay cached (re-read by k_cell within ~10us).
__global__ __launch_bounds__(256, 2) void k_gates(
    const float* __restrict__ w_ih, const float* __restrict__ w_hh,
    const unsigned short* __restrict__ hh, const unsigned short* __restrict__ hm,
    const float* __restrict__ embed, unsigned long long* __restrict__ slots,
    int t, float* __restrict__ sym_out, float* __restrict__ gp)
{
    __shared__ __align__(16) unsigned char smem[2][16384];
    const int nbi = blockIdx.x, y = blockIdx.y, z = blockIdx.z;
    const float* W = (y ? w_hh : w_ih) + (size_t)nbi * 65536 + z * 256;
    float* gout = gp + (size_t)(y * 4 + z) * (Bdim * 4096);
    if (y)
        mm_core<4, 8, false, false, false, false>(&smem[0][0], nullptr, W,
            hh + z * 256, hm + z * 256, nullptr, nullptr, t, nullptr,
            nbi * 64, nullptr, gout, 4096, nullptr);
    else
        mm_core<4, 8, false, false, true, false>(&smem[0][0], nullptr, W,
            nullptr, nullptr, embed + z * 256, slots, t,
            ((nbi == 0 && z == 0) ? sym_out : nullptr),
            nbi * 64, nullptr, gout, 4096, nullptr);
}

// LSTM elementwise: gates = sum of 8 partials + b_ih + b_hh (fixed order).
// Emits h as 2 bf16 planes for the next GEMMs; resets argmax slots.
__global__ void k_cell(const float* __restrict__ gp, const float* __restrict__ b_ih,
                       const float* __restrict__ b_hh, float* __restrict__ cbuf,
                       unsigned short* __restrict__ hh, unsigned short* __restrict__ hm,
                       unsigned long long* __restrict__ slots)
{
    const int idx = blockIdx.x * 256 + threadIdx.x;   // 0..65535
    const int b = idx >> 10, k = idx & 1023;
    const size_t S = (size_t)Bdim * 4096;
    const size_t base = (size_t)b * 4096;
    float g[4];
#pragma unroll
    for (int q = 0; q < 4; q++) {
        size_t o = base + q * 1024 + k;
        float s = gp[o];
#pragma unroll
        for (int i = 1; i < 8; i++) s += gp[i * S + o];
        g[q] = s + b_ih[q * 1024 + k] + b_hh[q * 1024 + k];
    }
    float si = 1.f / (1.f + expf(-g[0]));
    float sf = 1.f / (1.f + expf(-g[1]));
    float so = 1.f / (1.f + expf(-g[3]));
    float c  = cbuf[idx];
    float c2 = sf * c + si * tanhf(g[2]);
    float h2 = so * tanhf(c2);
    cbuf[idx] = c2;
    unsigned short hs, ms;
    bsplit2(h2, hs, ms);
    const size_t o = (size_t)b * 1024 + k;
    hh[o] = hs; hm[o] = ms;
    if (idx < 64) slots[idx] = 0ull;   // reset for upcoming k_logits argmax
}

// initial state: sym[:,0] = SOS(=1), xs = split(embed[1]), h = split(h0), c = c0
__global__ void k_init(const float* __restrict__ embed, const float* __restrict__ h0,
                       const float* __restrict__ c0,
                       unsigned short* __restrict__ xsh, unsigned short* __restrict__ xsm,
                       unsigned short* __restrict__ hh, unsigned short* __restrict__ hm,
                       float* __restrict__ cbuf, float* __restrict__ sym_out,
                       unsigned long long* __restrict__ slots)
{
    const int b = blockIdx.x, t4 = threadIdx.x * 4;
    if (threadIdx.x == 0) { sym_out[b * Tdim] = 1.0f; slots[b] = 0ull; }
    const size_t o = (size_t)b * 1024 + t4;
    ushort4 hi4, mi4;

    float4 e = *(const float4*)(embed + 1024 + t4);     // embed[SOS=1]
    bsplit2(e.x, hi4.x, mi4.x);
    bsplit2(e.y, hi4.y, mi4.y);
    bsplit2(e.z, hi4.z, mi4.z);
    bsplit2(e.w, hi4.w, mi4.w);
    *(ushort4*)(xsh + o) = hi4; *(ushort4*)(xsm + o) = mi4;

    float4 hv = *(const float4*)(h0 + (size_t)b * 1024 + t4);
    bsplit2(hv.x, hi4.x, mi4.x);
    bsplit2(hv.y, hi4.y, mi4.y);
    bsplit2(hv.z, hi4.z, mi4.z);
    bsplit2(hv.w, hi4.w, mi4.w);
    *(ushort4*)(hh + o) = hi4; *(ushort4*)(hm + o) = mi4;

    float4 cv = *(const float4*)(c0 + (size_t)b * 1024 + t4);
    *(float4*)(cbuf + (size_t)b * 1024 + t4) = cv;
}

// final symbol from the last k_logits' slots (kernel-boundary coherent)
__global__ void k_symfinal(const unsigned long long* __restrict__ slots,
                           float* __restrict__ sym_out)
{
    const int b = threadIdx.x;
    sym_out[b * Tdim + (Tdim - 1)] = (float)decode_key(slots[b]);
}

extern "C" void kernel_launch(void* const* d_in, const int* in_sizes, int n_in,
                              void* d_out, int out_size, void* d_ws, size_t ws_size,
                              hipStream_t stream)
{
    // setup_inputs order:
    // 0 output (unused), 1 h0, 2 c0, 3 target_outputs (unused), 4 target_lengths (unused),
    // 5 embed, 6 w_ih, 7 w_hh, 8 b_ih, 9 b_hh, 10 w_out, 11 b_out
    const float* h0    = (const float*)d_in[1];
    const float* c0    = (const float*)d_in[2];
    const float* embed = (const float*)d_in[5];
    const float* w_ih  = (const float*)d_in[6];
    const float* w_hh  = (const float*)d_in[7];
    const float* b_ih  = (const float*)d_in[8];
    const float* b_hh  = (const float*)d_in[9];
    const float* w_out = (const float*)d_in[10];
    const float* b_out = (const float*)d_in[11];

    float* out = (float*)d_out;                       // [B][T][V] then [B][T] symbols (as f32)
    float* sym_out = out + (size_t)Bdim * Tdim * Vdim;

    // workspace (~9 MB): h planes + SOS-x planes (each [64][1024] u16),
    // cbuf [64][1024] f32, gp [8][64][4096] f32 partials, slots[64]
    unsigned short* hh  = (unsigned short*)d_ws;
    unsigned short* hm  = hh + (size_t)Bdim * 1024;
    unsigned short* xsh = hm + (size_t)Bdim * 1024;
    unsigned short* xsm = xsh + (size_t)Bdim * 1024;
    float* cbuf = (float*)(xsm + (size_t)Bdim * 1024);
    float* gp   = cbuf + (size_t)Bdim * Hdim;
    unsigned long long* slots = (unsigned long long*)(gp + 8ull * Bdim * 4096);

    k_init<<<Bdim, 256, 0, stream>>>(embed, h0, c0, xsh, xsm,
                                     hh, hm, cbuf, sym_out, slots);

    // decs[0] = embed[SOS] @ w_out.T + b_out (no argmax)
    k_logits<false><<<Vdim / 128, 512, 0, stream>>>(w_out, xsh, xsm,
                                                    b_out, out, slots);

    for (int t = 0; t < Tdim - 1; t++) {
        k_gates<<<dim3(64, 2, 4), 256, 0, stream>>>(w_ih, w_hh, hh, hm,
                                                    embed, slots, t, sym_out, gp);
        k_cell<<<Bdim * Hdim / 256, 256, 0, stream>>>(gp, b_ih, b_hh, cbuf,
                                                      hh, hm, slots);
        k_logits<true><<<Vdim / 128, 512, 0, stream>>>(w_out, hh, hm,
                                                       b_out, out + (size_t)(t + 1) * Vdim,
                                                       slots);
    }
    k_symfinal<<<1, 64, 0, stream>>>(slots, sym_out);
}